// Round 14
// baseline (352.717 us; speedup 1.0000x reference)
//
#include <hip/hip_runtime.h>
#include <hip/hip_bf16.h>

#define N_NODES 100000
#define N_EDGES 1600000
#define IN_DIM  128
#define HID     256
#define OUT_DIM 128
#define BN_EPS  1e-5f

typedef unsigned int u32;
typedef unsigned short u16;
typedef __attribute__((ext_vector_type(8))) short short8v;
typedef __attribute__((ext_vector_type(4))) float f32x4;

__device__ __forceinline__ float bf2f(u16 h) {
    return __uint_as_float(((u32)h) << 16);
}
__device__ __forceinline__ u16 f2bf(float f) {
    u32 u = __float_as_uint(f);
    u32 r = (u + 0x7fffu + ((u >> 16) & 1u)) >> 16;   // round-to-nearest-even
    return (u16)r;
}
__device__ __forceinline__ u32 pack2(float a, float b) {
    return (u32)f2bf(a) | ((u32)f2bf(b) << 16);
}
__device__ __forceinline__ void gload16(const void* g, void* l) {
    __builtin_amdgcn_global_load_lds((const __attribute__((address_space(1))) u32*)g,
                                     (__attribute__((address_space(3))) u32*)l, 16, 0, 0);
}
#define MFMA(a,b,c) __builtin_amdgcn_mfma_f32_16x16x32_bf16(a, b, c, 0, 0, 0)

// ---------------- fused prep: x->bf16, linked-list build, W transpose, stats zero ----
__global__ __launch_bounds__(256) void k_prep(const float* __restrict__ x,
                                              const int* __restrict__ ei,
                                              const float* __restrict__ W1,
                                              const float* __restrict__ W2,
                                              uint2* __restrict__ xb,
                                              int* __restrict__ head2,
                                              int2* __restrict__ nxt,
                                              char* __restrict__ w1t,
                                              char* __restrict__ w2t,
                                              float* __restrict__ gstats) {
    int t = blockIdx.x * 256 + threadIdx.x;     // grid = 12500*256 = 3.2M exact
    {   // x -> bf16 packed (t = float4 index, 3.2M total)
        float4 v = ((const float4*)x)[t];
        uint2 p;
        p.x = pack2(v.x, v.y);
        p.y = pack2(v.z, v.w);
        xb[t] = p;
    }
    if (t < N_EDGES) {   // linked-list: two parity chains per node
        int dst = ei[N_EDGES + t];
        int src = ei[t];
        int old = atomicExch(&head2[dst * 2 + (t & 1)], t);
        nxt[t] = make_int2(old, src);
    }
    if (t < 768) gstats[t] = 0.f;               // gstats(512) + gstats2(256)
    if (t < 8192) {      // W1->W1T, W2->W2T (bf16, transposed, pre-swizzled for LDS)
        u16 tmp[8];
        if (t < 4096) {
            int j = t >> 4, kc = t & 15;          // W1T: [256 j][128 k]
            #pragma unroll
            for (int i = 0; i < 8; ++i) tmp[i] = f2bf(W1[(kc * 8 + i) * HID + j]);
            u32 off = ((u32)(j * 256 + kc * 16)) ^ (((u32)(j & 7)) << 4);
            uint4 q;
            q.x = (u32)tmp[0] | ((u32)tmp[1] << 16);
            q.y = (u32)tmp[2] | ((u32)tmp[3] << 16);
            q.z = (u32)tmp[4] | ((u32)tmp[5] << 16);
            q.w = (u32)tmp[6] | ((u32)tmp[7] << 16);
            *(uint4*)(w1t + off) = q;
        } else {
            int t2 = t - 4096;
            int j = t2 >> 5, kc = t2 & 31;        // W2T: [128 j][256 k]
            #pragma unroll
            for (int i = 0; i < 8; ++i) tmp[i] = f2bf(W2[(kc * 8 + i) * OUT_DIM + j]);
            u32 off = ((u32)(j * 512 + kc * 16)) ^ (((u32)(j & 7)) << 4);
            uint4 q;
            q.x = (u32)tmp[0] | ((u32)tmp[1] << 16);
            q.y = (u32)tmp[2] | ((u32)tmp[3] << 16);
            q.z = (u32)tmp[4] | ((u32)tmp[5] << 16);
            q.w = (u32)tmp[6] | ((u32)tmp[7] << 16);
            *(uint4*)(w2t + off) = q;
        }
    }
}

// ---------------- FUSED aggregate + gemm1 ----------------
// Phase 1: chain-walk 160 nodes -> swizzled A tile directly in LDS (no aggrb buffer)
// Phase 2: R10 gemm1 MFMA (B half-K direct-copied from pre-swizzled w1t)
__global__ __launch_bounds__(512, 4) void k_fused1(const uint4* __restrict__ xb4,
                                                   const int2* __restrict__ nxt,
                                                   const int* __restrict__ head2,
                                                   const float* __restrict__ epsp,
                                                   const char* __restrict__ w1t,
                                                   const float* __restrict__ b1,
                                                   u16* __restrict__ h1t,
                                                   float* __restrict__ gstats) {
    __shared__ u16 Als[160 * 128];    // 40 KB swizzled A, produced by phase 1
    __shared__ u16 Bls[256 * 64];     // 32 KB swizzled, half K
    __shared__ float slds[512];

    const int tid = threadIdx.x, lane = tid & 63, w = tid >> 6;
    const int wr = w >> 2, wc = w & 3;
    const int base = blockIdx.x * 160;
    char* lA = (char*)Als;
    char* lB = (char*)Bls;

    slds[tid] = 0.f;

    // ---- phase 1: aggregate (R8 quarter-wave form), 10 rounds x 16 nodes ----
    {
        const int q = lane >> 4, l = lane & 15;     // quarter, lane-in-quarter
        const int nq = q >> 1, p = q & 1;           // node-in-pair, parity chain
        const float sc = 1.0f + epsp[0];
        for (int r = 0; r < 10; ++r) {
            const int row = r * 16 + w * 2 + nq;    // 0..159 (row&7 == node&7)
            const int node = base + row;
            float a[8];
            #pragma unroll
            for (int i = 0; i < 8; ++i) a[i] = 0.f;
            if (p == 0) {   // self term (1+eps)*x
                uint4 v = xb4[node * 16 + l];
                a[0] = bf2f((u16)v.x) * sc;  a[1] = bf2f((u16)(v.x >> 16)) * sc;
                a[2] = bf2f((u16)v.y) * sc;  a[3] = bf2f((u16)(v.y >> 16)) * sc;
                a[4] = bf2f((u16)v.z) * sc;  a[5] = bf2f((u16)(v.z >> 16)) * sc;
                a[6] = bf2f((u16)v.w) * sc;  a[7] = bf2f((u16)(v.w >> 16)) * sc;
            }
            int e = head2[node * 2 + p];
            while (e >= 0) {
                int2 nv = nxt[e];           // quarter-uniform -> broadcast
                e = nv.x;
                uint4 v = xb4[nv.y * 16 + l];
                a[0] += bf2f((u16)v.x);  a[1] += bf2f((u16)(v.x >> 16));
                a[2] += bf2f((u16)v.y);  a[3] += bf2f((u16)(v.y >> 16));
                a[4] += bf2f((u16)v.z);  a[5] += bf2f((u16)(v.z >> 16));
                a[6] += bf2f((u16)v.w);  a[7] += bf2f((u16)(v.w >> 16));
            }
            #pragma unroll
            for (int i = 0; i < 8; ++i) a[i] += __shfl_xor(a[i], 16);   // merge parities
            if (p == 0) {
                uint4 o;
                o.x = pack2(a[0], a[1]);
                o.y = pack2(a[2], a[3]);
                o.z = pack2(a[4], a[5]);
                o.w = pack2(a[6], a[7]);
                u32 b = ((u32)row * 256 + (u32)l * 16) ^ (((u32)(row & 7)) << 4);
                *(uint4*)(lA + b) = o;
            }
        }
    }

    // ---- phase 2: MFMA (R10 gemm1 structure) ----
    const int rA = lane & 15;
    const int q = lane >> 4;
    const int kb = q << 3;
    const u32 xsw = ((u32)(rA & 7)) << 4;
    int colv[4]; float bcol[4];
    #pragma unroll
    for (int n = 0; n < 4; ++n) { colv[n] = wc * 64 + n * 16 + rA; bcol[n] = b1[colv[n]]; }

    f32x4 acc[5][4];
    #pragma unroll
    for (int m = 0; m < 5; ++m)
        #pragma unroll
        for (int n = 0; n < 4; ++n) acc[m][n] = (f32x4){0.f, 0.f, 0.f, 0.f};

    for (int kh = 0; kh < 2; ++kh) {
        if (kh) __syncthreads();     // prev half's Bls reads done before overwrite
        // stage B half-K: direct byte copy of physical (swizzled) half-row slices
        #pragma unroll
        for (int i = 0; i < 4; ++i) {
            int idx = i * 512 + tid;
            int j = idx >> 3, kc8 = idx & 7;
            gload16(w1t + (u32)j * 256 + (u32)kh * 128 + (u32)kc8 * 16, lB + idx * 16);
        }
        asm volatile("s_waitcnt vmcnt(0)" ::: "memory");
        __syncthreads();   // B landed + (kh==0) all waves' A writes visible

        #pragma unroll
        for (int ksl = 0; ksl < 2; ++ksl) {
            const int kk2A = (kh * 64 + ksl * 32 + kb) * 2;
            const int kk2B = (ksl * 32 + kb) * 2;
            short8v a[5], b[4];
            #pragma unroll
            for (int m = 0; m < 5; ++m) {
                u32 off = ((u32)((wr * 80 + m * 16 + rA) * 256 + kk2A)) ^ xsw;
                a[m] = *(const short8v*)(lA + off);
            }
            #pragma unroll
            for (int n = 0; n < 4; ++n) {
                u32 off = ((u32)(colv[n] * 128 + kk2B)) ^ xsw;
                b[n] = *(const short8v*)(lB + off);
            }
            #pragma unroll
            for (int m = 0; m < 5; ++m)
                #pragma unroll
                for (int n = 0; n < 4; ++n)
                    acc[m][n] = MFMA(a[m], b[n], acc[m][n]);
        }
    }

    // epilogue: tile-col-major coalesced stores (wave writes dense 512B per (m,n))
    const int Tb = blockIdx.x * 10 + wr * 5;
    float csum[4] = {0.f,0.f,0.f,0.f}, csq[4] = {0.f,0.f,0.f,0.f};
    #pragma unroll
    for (int m = 0; m < 5; ++m) {
        int T = Tb + m;
        #pragma unroll
        for (int n = 0; n < 4; ++n) {
            f32x4 d = acc[m][n];
            float v0 = d[0] + bcol[n], v1 = d[1] + bcol[n];
            float v2 = d[2] + bcol[n], v3 = d[3] + bcol[n];
            csum[n] += v0 + v1 + v2 + v3;
            csq[n]  += v0*v0 + v1*v1 + v2*v2 + v3*v3;
            uint2 p; p.x = pack2(v0, v1); p.y = pack2(v2, v3);
            *(uint2*)(h1t + (size_t)T * 4096 + colv[n] * 16 + q * 4) = p;
        }
    }
    #pragma unroll
    for (int n = 0; n < 4; ++n) {
        csum[n] += __shfl_xor(csum[n], 16); csum[n] += __shfl_xor(csum[n], 32);
        csq[n]  += __shfl_xor(csq[n], 16);  csq[n]  += __shfl_xor(csq[n], 32);
    }
    if (lane < 16) {
        #pragma unroll
        for (int n = 0; n < 4; ++n) {
            atomicAdd(&slds[colv[n]], csum[n]);
            atomicAdd(&slds[256 + colv[n]], csq[n]);
        }
    }
    __syncthreads();
    atomicAdd(&gstats[tid], slds[tid]);
}

// ---------------- MFMA gemm2: h2t = relu(bn1(h1t)) @ W2 + b2 (bf16 tiled), stats2 ----
__global__ __launch_bounds__(512) void k_gemm2(const uint4* __restrict__ h1t4,
                                               const char* __restrict__ w2t,
                                               const float* __restrict__ b2,
                                               const float* __restrict__ g1,
                                               const float* __restrict__ beta1,
                                               const float* __restrict__ gstats,
                                               u16* __restrict__ h2t,
                                               float* __restrict__ gstats2) {
    __shared__ u16 Als[160 * 128];    // 40 KB (K half), swizzled [row][k] u16
    __shared__ u16 Bls[128 * 128];    // 32 KB (K half), swizzled
    __shared__ float a1s[256], b1s[256];
    __shared__ float slds[256];

    const int tid = threadIdx.x, lane = tid & 63, w = tid >> 6;
    const int wr = w >> 2, wc = w & 3;
    const int Tbase = blockIdx.x * 10;

    if (tid < 256) {
        float s = gstats[tid], sq = gstats[256 + tid];
        float mu = s * (1.0f / N_NODES);
        float var = sq * (1.0f / N_NODES) - mu * mu;
        float inv = rsqrtf(var + BN_EPS);
        float a = g1[tid] * inv;
        a1s[tid] = a;
        b1s[tid] = beta1[tid] - mu * a;
        slds[tid] = 0.f;
    }

    char* lA = (char*)Als;
    char* lB = (char*)Bls;

    const int rA = lane & 15;
    const int q = lane >> 4;
    const int kb = q << 3;
    const u32 xsw = ((u32)(rA & 7)) << 4;
    int colv[2]; float bcol[2];
    #pragma unroll
    for (int n = 0; n < 2; ++n) { colv[n] = wc * 32 + n * 16 + rA; bcol[n] = b2[colv[n]]; }

    __syncthreads();   // a1s/b1s ready

    f32x4 acc[5][2];
    #pragma unroll
    for (int m = 0; m < 5; ++m)
        #pragma unroll
        for (int n = 0; n < 2; ++n) acc[m][n] = (f32x4){0.f, 0.f, 0.f, 0.f};

    for (int kh = 0; kh < 2; ++kh) {
        // stage A half-tile with BN1+ReLU from tile-col-major h1t (tile = 512 uint4)
        #pragma unroll
        for (int i = 0; i < 5; ++i) {
            int id = i * 512 + tid;        // 0..2559
            int kl = id & 127;
            int h16 = (id >> 7) & 1;
            int Tl = id >> 8;              // 0..9
            int kg = kh * 128 + kl;
            uint4 v = h1t4[(size_t)(Tbase + Tl) * 512 + kg * 2 + h16];
            float a = a1s[kg], b = b1s[kg];
            int r0 = Tl * 16 + h16 * 8;
            u16 hv[8] = {(u16)v.x, (u16)(v.x >> 16), (u16)v.y, (u16)(v.y >> 16),
                         (u16)v.z, (u16)(v.z >> 16), (u16)v.w, (u16)(v.w >> 16)};
            #pragma unroll
            for (int rr = 0; rr < 8; ++rr) {
                float f = fmaxf(bf2f(hv[rr]) * a + b, 0.f);
                int r = r0 + rr;
                u32 off = ((u32)(r * 256 + kl * 2)) ^ (((u32)(r & 7)) << 4);
                *(u16*)(lA + off) = f2bf(f);
            }
        }
        // stage B half-K: direct byte copy of physical (swizzled) half-row slices
        #pragma unroll
        for (int i = 0; i < 4; ++i) {
            int idx = i * 512 + tid;
            int j = idx >> 4, kc16 = idx & 15;
            u32 src = (u32)j * 512 + (u32)kh * 256 + (u32)kc16 * 16;   // swizzle preserved
            gload16(w2t + src, lB + idx * 16);
        }
        asm volatile("s_waitcnt vmcnt(0)" ::: "memory");
        __syncthreads();

        #pragma unroll
        for (int ks = 0; ks < 4; ++ks) {
            const int kk2 = (ks * 32 + kb) * 2;
            short8v a[5], b[2];
            #pragma unroll
            for (int n = 0; n < 2; ++n) {
                u32 off = ((u32)(colv[n] * 256 + kk2)) ^ xsw;
                b[n] = *(const short8v*)(lB + off);
            }
            #pragma unroll
            for (int m = 0; m < 5; ++m) {
                u32 off = ((u32)((wr * 80 + m * 16 + rA) * 256 + kk2)) ^ xsw;
                a[m] = *(const short8v*)(lA + off);
            }
            #pragma unroll
            for (int m = 0; m < 5; ++m)
                #pragma unroll
                for (int n = 0; n < 2; ++n)
                    acc[m][n] = MFMA(a[m], b[n], acc[m][n]);
        }
        __syncthreads();   // Als/Bls reads done before restage / epilogue
    }

    // epilogue: tile-col-major h2t (u16 idx = T*2048 + col*16 + row), coalesced
    const int Tb = Tbase + wr * 5;
    float csum[2] = {0.f,0.f}, csq[2] = {0.f,0.f};
    #pragma unroll
    for (int m = 0; m < 5; ++m) {
        int T = Tb + m;
        #pragma unroll
        for (int n = 0; n < 2; ++n) {
            f32x4 d = acc[m][n];
            float v0 = d[0] + bcol[n], v1 = d[1] + bcol[n];
            float v2 = d[2] + bcol[n], v3 = d[3] + bcol[n];
            csum[n] += v0 + v1 + v2 + v3;
            csq[n]  += v0*v0 + v1*v1 + v2*v2 + v3*v3;
            uint2 p; p.x = pack2(v0, v1); p.y = pack2(v2, v3);
            *(uint2*)(h2t + (size_t)T * 2048 + colv[n] * 16 + q * 4) = p;
        }
    }
    #pragma unroll
    for (int n = 0; n < 2; ++n) {
        csum[n] += __shfl_xor(csum[n], 16); csum[n] += __shfl_xor(csum[n], 32);
        csq[n]  += __shfl_xor(csq[n], 16);  csq[n]  += __shfl_xor(csq[n], 32);
    }
    if (lane < 16) {
        #pragma unroll
        for (int n = 0; n < 2; ++n) {
            atomicAdd(&slds[colv[n]], csum[n]);
            atomicAdd(&slds[128 + colv[n]], csq[n]);
        }
    }
    __syncthreads();
    if (tid < 256) atomicAdd(&gstats2[tid], slds[tid]);
}

// ---------------- out = relu(bn2(h2t)) : tiled bf16 in -> row-major f32 out ----------
__global__ __launch_bounds__(256) void k_bn2(const uint4* __restrict__ h2t4,
                                             float* __restrict__ out,
                                             const float* __restrict__ gstats2,
                                             const float* __restrict__ g2,
                                             const float* __restrict__ beta2) {
    __shared__ float fl[32 * 128];     // 16 KB: [32 rows][128 cols] f32
    __shared__ float a2s[128], b2s[128];
    const int tid = threadIdx.x;
    if (tid < 128) {
        float s = gstats2[tid], sq = gstats2[128 + tid];
        float mu = s * (1.0f / N_NODES);
        float var = sq * (1.0f / N_NODES) - mu * mu;
        float inv = rsqrtf(var + BN_EPS);
        float a = g2[tid] * inv;
        a2s[tid] = a;
        b2s[tid] = beta2[tid] - mu * a;
    }
    __syncthreads();
    const int Tbase = blockIdx.x * 2;     // 2 tiles = 32 rows per block, 3125 blocks
    // 2 tiles x 128 cols x 2 halves = 512 uint4 reads -> 2 iterations of 256 threads
    #pragma unroll
    for (int i = 0; i < 2; ++i) {
        int id = i * 256 + tid;            // 0..511
        int kl = id & 127;
        int h16 = (id >> 7) & 1;
        int Tl = id >> 8;                  // 0..1
        uint4 v = h2t4[(size_t)(Tbase + Tl) * 256 + kl * 2 + h16];
        float a = a2s[kl], b = b2s[kl];
        int r0 = Tl * 16 + h16 * 8;
        u16 hv[8] = {(u16)v.x, (u16)(v.x >> 16), (u16)v.y, (u16)(v.y >> 16),
                     (u16)v.z, (u16)(v.z >> 16), (u16)v.w, (u16)(v.w >> 16)};
        #pragma unroll
        for (int rr = 0; rr < 8; ++rr)
            fl[(r0 + rr) * 128 + kl] = fmaxf(bf2f(hv[rr]) * a + b, 0.f);
    }
    __syncthreads();
    #pragma unroll
    for (int i = 0; i < 4; ++i) {
        int id = i * 256 + tid;            // 0..1023
        int row = id >> 5;                 // 0..31
        int ch = id & 31;                  // float4 within row
        float4 vv = *(const float4*)&fl[row * 128 + ch * 4];
        ((float4*)out)[(size_t)(blockIdx.x * 32 + row) * 32 + ch] = vv;
    }
}

extern "C" void kernel_launch(void* const* d_in, const int* in_sizes, int n_in,
                              void* d_out, int out_size, void* d_ws, size_t ws_size,
                              hipStream_t stream) {
    const float* x     = (const float*)d_in[0];
    const int*   ei    = (const int*)d_in[1];
    const float* epsp  = (const float*)d_in[2];
    const float* W1    = (const float*)d_in[3];
    const float* b1    = (const float*)d_in[4];
    const float* g1    = (const float*)d_in[5];
    const float* beta1 = (const float*)d_in[6];
    const float* W2    = (const float*)d_in[7];
    const float* b2    = (const float*)d_in[8];
    const float* g2    = (const float*)d_in[9];
    const float* beta2 = (const float*)d_in[10];

    char* ws = (char*)d_ws;
    u16*   h1t     = (u16*)ws;                      // [0, 51.2M) bf16 tiled [6250][256][16]
    u16*   h2t     = (u16*)(ws + 51200000);         // [51.2M, 76.8M) tiled h2 (overlays dead chain data)
    // chain data (dead after k_fused1):
    int2*  nxt     = (int2*)(ws + 51200000);        // 12.8 MB (next, src) per edge
    int*   head2   = (int*)(ws + 64000000);         // 800 KB (two parity chains/node)
    uint2* xb      = (uint2*)(ws + 64800000);       // 25.6 MB bf16 [N][128]
    float* gstats  = (float*)(ws + 90400000);       // 512 f32 + 256 f32
    float* gstats2 = gstats + 512;
    char*  w1t     = ws + 90404096;                 // 64 KB bf16 W1^T pre-swizzled
    char*  w2t     = ws + 90469632;                 // 64 KB bf16 W2^T pre-swizzled
    float* out = (float*)d_out;

    hipMemsetAsync(head2, 0xFF, 800000, stream);    // head = -1

    k_prep<<<12500, 256, 0, stream>>>(x, ei, W1, W2, xb, head2, nxt, w1t, w2t, gstats);
    k_fused1<<<625, 512, 0, stream>>>((const uint4*)xb, nxt, head2, epsp, w1t, b1, h1t, gstats);
    k_gemm2<<<625, 512, 0, stream>>>((const uint4*)h1t, w2t, b2, g1, beta1, gstats, h2t, gstats2);
    k_bn2<<<3125, 256, 0, stream>>>((const uint4*)h2t, out, gstats2, g2, beta2);
}

// Round 15
// 351.319 us; speedup vs baseline: 1.0040x; 1.0040x over previous
//
#include <hip/hip_runtime.h>
#include <hip/hip_bf16.h>

#define N_NODES 100000
#define N_EDGES 1600000
#define IN_DIM  128
#define HID     256
#define OUT_DIM 128
#define BN_EPS  1e-5f

typedef unsigned int u32;
typedef unsigned short u16;
typedef __attribute__((ext_vector_type(8))) short short8v;
typedef __attribute__((ext_vector_type(4))) float f32x4;

__device__ __forceinline__ float bf2f(u16 h) {
    return __uint_as_float(((u32)h) << 16);
}
__device__ __forceinline__ u16 f2bf(float f) {
    u32 u = __float_as_uint(f);
    u32 r = (u + 0x7fffu + ((u >> 16) & 1u)) >> 16;   // round-to-nearest-even
    return (u16)r;
}
__device__ __forceinline__ u32 pack2(float a, float b) {
    return (u32)f2bf(a) | ((u32)f2bf(b) << 16);
}
__device__ __forceinline__ void gload16(const void* g, void* l) {
    __builtin_amdgcn_global_load_lds((const __attribute__((address_space(1))) u32*)g,
                                     (__attribute__((address_space(3))) u32*)l, 16, 0, 0);
}
#define MFMA(a,b,c) __builtin_amdgcn_mfma_f32_16x16x32_bf16(a, b, c, 0, 0, 0)

// ---------------- fused prep: x->bf16, linked-list build, W transpose, stats zero ----
__global__ __launch_bounds__(256) void k_prep(const float* __restrict__ x,
                                              const int* __restrict__ ei,
                                              const float* __restrict__ W1,
                                              const float* __restrict__ W2,
                                              uint2* __restrict__ xb,
                                              int* __restrict__ head2,
                                              int2* __restrict__ nxt,
                                              char* __restrict__ w1t,
                                              char* __restrict__ w2t,
                                              float* __restrict__ gstats) {
    int t = blockIdx.x * 256 + threadIdx.x;     // grid = 12500*256 = 3.2M exact
    {   // x -> bf16 packed (t = float4 index, 3.2M total)
        float4 v = ((const float4*)x)[t];
        uint2 p;
        p.x = pack2(v.x, v.y);
        p.y = pack2(v.z, v.w);
        xb[t] = p;
    }
    if (t < N_EDGES) {   // linked-list: two parity chains per node
        int dst = ei[N_EDGES + t];
        int src = ei[t];
        int old = atomicExch(&head2[dst * 2 + (t & 1)], t);
        nxt[t] = make_int2(old, src);
    }
    if (t < 768) gstats[t] = 0.f;               // gstats(512) + gstats2(256)
    if (t < 8192) {      // W1->W1T, W2->W2T (bf16, transposed, pre-swizzled for LDS)
        u16 tmp[8];
        if (t < 4096) {
            int j = t >> 4, kc = t & 15;          // W1T: [256 j][128 k]
            #pragma unroll
            for (int i = 0; i < 8; ++i) tmp[i] = f2bf(W1[(kc * 8 + i) * HID + j]);
            u32 off = ((u32)(j * 256 + kc * 16)) ^ (((u32)(j & 7)) << 4);
            uint4 q;
            q.x = (u32)tmp[0] | ((u32)tmp[1] << 16);
            q.y = (u32)tmp[2] | ((u32)tmp[3] << 16);
            q.z = (u32)tmp[4] | ((u32)tmp[5] << 16);
            q.w = (u32)tmp[6] | ((u32)tmp[7] << 16);
            *(uint4*)(w1t + off) = q;
        } else {
            int t2 = t - 4096;
            int j = t2 >> 5, kc = t2 & 31;        // W2T: [128 j][256 k]
            #pragma unroll
            for (int i = 0; i < 8; ++i) tmp[i] = f2bf(W2[(kc * 8 + i) * OUT_DIM + j]);
            u32 off = ((u32)(j * 512 + kc * 16)) ^ (((u32)(j & 7)) << 4);
            uint4 q;
            q.x = (u32)tmp[0] | ((u32)tmp[1] << 16);
            q.y = (u32)tmp[2] | ((u32)tmp[3] << 16);
            q.z = (u32)tmp[4] | ((u32)tmp[5] << 16);
            q.w = (u32)tmp[6] | ((u32)tmp[7] << 16);
            *(uint4*)(w2t + off) = q;
        }
    }
}

// ---------------- gather-aggregate: quarter-wave per (node,parity) chain (R8 form) ----
__global__ __launch_bounds__(256) void k_aggregate(const uint4* __restrict__ xb4,
                                                   const int2* __restrict__ nxt,
                                                   const int* __restrict__ head2,
                                                   const float* __restrict__ epsp,
                                                   char* __restrict__ aggrb) {
    const int lane = threadIdx.x & 63;
    const int w = threadIdx.x >> 6;
    const int q = lane >> 4, l = lane & 15;     // quarter, lane-in-quarter
    const int nq = q >> 1, p = q & 1;           // node-in-wave, parity chain
    const int node = blockIdx.x * 8 + w * 2 + nq;

    float a[8];
    #pragma unroll
    for (int i = 0; i < 8; ++i) a[i] = 0.f;

    if (p == 0) {   // self term (1+eps)*x
        float sc = 1.0f + epsp[0];
        uint4 v = xb4[node * 16 + l];
        a[0] = bf2f((u16)v.x) * sc;  a[1] = bf2f((u16)(v.x >> 16)) * sc;
        a[2] = bf2f((u16)v.y) * sc;  a[3] = bf2f((u16)(v.y >> 16)) * sc;
        a[4] = bf2f((u16)v.z) * sc;  a[5] = bf2f((u16)(v.z >> 16)) * sc;
        a[6] = bf2f((u16)v.w) * sc;  a[7] = bf2f((u16)(v.w >> 16)) * sc;
    }
    int e = head2[node * 2 + p];
    while (e >= 0) {
        int2 nv = nxt[e];           // quarter-uniform -> broadcast
        e = nv.x;
        uint4 v = xb4[nv.y * 16 + l];
        a[0] += bf2f((u16)v.x);  a[1] += bf2f((u16)(v.x >> 16));
        a[2] += bf2f((u16)v.y);  a[3] += bf2f((u16)(v.y >> 16));
        a[4] += bf2f((u16)v.z);  a[5] += bf2f((u16)(v.z >> 16));
        a[6] += bf2f((u16)v.w);  a[7] += bf2f((u16)(v.w >> 16));
    }
    #pragma unroll
    for (int i = 0; i < 8; ++i) a[i] += __shfl_xor(a[i], 16);   // merge parities
    if (p == 0) {
        uint4 o;
        o.x = pack2(a[0], a[1]);
        o.y = pack2(a[2], a[3]);
        o.z = pack2(a[4], a[5]);
        o.w = pack2(a[6], a[7]);
        u32 b = ((u32)node * 256 + (u32)l * 16) ^ (((u32)(node & 7)) << 4);  // pre-swizzle
        *(uint4*)(aggrb + b) = o;
    }
}

// ---------------- MFMA gemm1: h1t = aggr @ W1 + b1 (bf16, tile-col-major), stats ----
// A and B both staged in half-K slices -> LDS 52 KB -> 3 blocks/CU
__global__ __launch_bounds__(512, 6) void k_gemm1(const char* __restrict__ aggrb,
                                                  const char* __restrict__ w1t,
                                                  const float* __restrict__ b1,
                                                  u16* __restrict__ h1t,
                                                  float* __restrict__ gstats) {
    __shared__ u16 Als[160 * 64];     // 20 KB swizzled, half K
    __shared__ u16 Bls[256 * 64];     // 32 KB swizzled, half K

    const int tid = threadIdx.x, lane = tid & 63, w = tid >> 6;
    const int wr = w >> 2, wc = w & 3;
    const int base = blockIdx.x * 160;

    char* lA = (char*)Als;
    char* lB = (char*)Bls;
    const char* ga = aggrb + (size_t)base * 256;

    const int rA = lane & 15;
    const int q = lane >> 4;
    const int kb = q << 3;
    const u32 xsw = ((u32)(rA & 7)) << 4;
    int colv[4]; float bcol[4];
    #pragma unroll
    for (int n = 0; n < 4; ++n) { colv[n] = wc * 64 + n * 16 + rA; bcol[n] = b1[colv[n]]; }

    f32x4 acc[5][4];
    #pragma unroll
    for (int m = 0; m < 5; ++m)
        #pragma unroll
        for (int n = 0; n < 4; ++n) acc[m][n] = (f32x4){0.f, 0.f, 0.f, 0.f};

    for (int kh = 0; kh < 2; ++kh) {
        if (kh) __syncthreads();     // prev half's LDS reads done before overwrite
        // stage A half-K: 160 rows x 8 chunks = 1280 x 16B (half-rows are swizzle-closed)
        #pragma unroll
        for (int i = 0; i < 3; ++i) {
            int idx = i * 512 + tid;
            if (idx < 1280) {        // wave-aligned mask (1280 = 2.5*512)
                int r = idx >> 3, cc = idx & 7;
                gload16(ga + r * 256 + kh * 128 + cc * 16, lA + idx * 16);
            }
        }
        // stage B half-K: 256 rows x 8 chunks = 2048 x 16B, direct copy (swizzle preserved)
        #pragma unroll
        for (int i = 0; i < 4; ++i) {
            int idx = i * 512 + tid;
            int j = idx >> 3, kc8 = idx & 7;
            gload16(w1t + (u32)j * 256 + (u32)kh * 128 + (u32)kc8 * 16, lB + idx * 16);
        }
        asm volatile("s_waitcnt vmcnt(0)" ::: "memory");
        __syncthreads();

        #pragma unroll
        for (int ksl = 0; ksl < 2; ++ksl) {
            const int kk2 = (ksl * 32 + kb) * 2;   // byte offset within 128B half-row
            short8v a[5], b[4];
            #pragma unroll
            for (int m = 0; m < 5; ++m) {
                u32 off = ((u32)((wr * 80 + m * 16 + rA) * 128 + kk2)) ^ xsw;
                a[m] = *(const short8v*)(lA + off);
            }
            #pragma unroll
            for (int n = 0; n < 4; ++n) {
                u32 off = ((u32)(colv[n] * 128 + kk2)) ^ xsw;
                b[n] = *(const short8v*)(lB + off);
            }
            #pragma unroll
            for (int m = 0; m < 5; ++m)
                #pragma unroll
                for (int n = 0; n < 4; ++n)
                    acc[m][n] = MFMA(a[m], b[n], acc[m][n]);
        }
    }

    // epilogue: tile-col-major coalesced stores; stats via shfl + direct global atomics
    const int Tb = blockIdx.x * 10 + wr * 5;
    float csum[4] = {0.f,0.f,0.f,0.f}, csq[4] = {0.f,0.f,0.f,0.f};
    #pragma unroll
    for (int m = 0; m < 5; ++m) {
        int T = Tb + m;
        #pragma unroll
        for (int n = 0; n < 4; ++n) {
            f32x4 d = acc[m][n];
            float v0 = d[0] + bcol[n], v1 = d[1] + bcol[n];
            float v2 = d[2] + bcol[n], v3 = d[3] + bcol[n];
            csum[n] += v0 + v1 + v2 + v3;
            csq[n]  += v0*v0 + v1*v1 + v2*v2 + v3*v3;
            uint2 p; p.x = pack2(v0, v1); p.y = pack2(v2, v3);
            *(uint2*)(h1t + (size_t)T * 4096 + colv[n] * 16 + q * 4) = p;
        }
    }
    #pragma unroll
    for (int n = 0; n < 4; ++n) {
        csum[n] += __shfl_xor(csum[n], 16); csum[n] += __shfl_xor(csum[n], 32);
        csq[n]  += __shfl_xor(csq[n], 16);  csq[n]  += __shfl_xor(csq[n], 32);
    }
    if (lane < 16) {
        #pragma unroll
        for (int n = 0; n < 4; ++n) {
            atomicAdd(&gstats[colv[n]], csum[n]);
            atomicAdd(&gstats[256 + colv[n]], csq[n]);
        }
    }
}

// ---------------- MFMA gemm2: h2t = relu(bn1(h1t)) @ W2 + b2 (bf16 tiled), stats2 ----
// B gloads issued BEFORE the A restage so HBM latency hides under the VALU work
__global__ __launch_bounds__(512) void k_gemm2(const uint4* __restrict__ h1t4,
                                               const char* __restrict__ w2t,
                                               const float* __restrict__ b2,
                                               const float* __restrict__ g1,
                                               const float* __restrict__ beta1,
                                               const float* __restrict__ gstats,
                                               u16* __restrict__ h2t,
                                               float* __restrict__ gstats2) {
    __shared__ u16 Als[160 * 128];    // 40 KB (K half), swizzled [row][k] u16
    __shared__ u16 Bls[128 * 128];    // 32 KB (K half), swizzled
    __shared__ float a1s[256], b1s[256];
    __shared__ float slds[256];

    const int tid = threadIdx.x, lane = tid & 63, w = tid >> 6;
    const int wr = w >> 2, wc = w & 3;
    const int Tbase = blockIdx.x * 10;

    if (tid < 256) {
        float s = gstats[tid], sq = gstats[256 + tid];
        float mu = s * (1.0f / N_NODES);
        float var = sq * (1.0f / N_NODES) - mu * mu;
        float inv = rsqrtf(var + BN_EPS);
        float a = g1[tid] * inv;
        a1s[tid] = a;
        b1s[tid] = beta1[tid] - mu * a;
        slds[tid] = 0.f;
    }

    char* lA = (char*)Als;
    char* lB = (char*)Bls;

    const int rA = lane & 15;
    const int q = lane >> 4;
    const int kb = q << 3;
    const u32 xsw = ((u32)(rA & 7)) << 4;
    int colv[2]; float bcol[2];
    #pragma unroll
    for (int n = 0; n < 2; ++n) { colv[n] = wc * 32 + n * 16 + rA; bcol[n] = b2[colv[n]]; }

    __syncthreads();   // a1s/b1s ready

    f32x4 acc[5][2];
    #pragma unroll
    for (int m = 0; m < 5; ++m)
        #pragma unroll
        for (int n = 0; n < 2; ++n) acc[m][n] = (f32x4){0.f, 0.f, 0.f, 0.f};

    for (int kh = 0; kh < 2; ++kh) {
        // issue B half-K gloads FIRST (latency hides under the A restage below)
        #pragma unroll
        for (int i = 0; i < 4; ++i) {
            int idx = i * 512 + tid;
            int j = idx >> 4, kc16 = idx & 15;
            u32 src = (u32)j * 512 + (u32)kh * 256 + (u32)kc16 * 16;   // swizzle preserved
            gload16(w2t + src, lB + idx * 16);
        }
        // stage A half-tile with BN1+ReLU from tile-col-major h1t (tile = 512 uint4)
        #pragma unroll
        for (int i = 0; i < 5; ++i) {
            int id = i * 512 + tid;        // 0..2559
            int kl = id & 127;
            int h16 = (id >> 7) & 1;
            int Tl = id >> 8;              // 0..9
            int kg = kh * 128 + kl;
            uint4 v = h1t4[(size_t)(Tbase + Tl) * 512 + kg * 2 + h16];
            float a = a1s[kg], b = b1s[kg];
            int r0 = Tl * 16 + h16 * 8;
            u16 hv[8] = {(u16)v.x, (u16)(v.x >> 16), (u16)v.y, (u16)(v.y >> 16),
                         (u16)v.z, (u16)(v.z >> 16), (u16)v.w, (u16)(v.w >> 16)};
            #pragma unroll
            for (int rr = 0; rr < 8; ++rr) {
                float f = fmaxf(bf2f(hv[rr]) * a + b, 0.f);
                int r = r0 + rr;
                u32 off = ((u32)(r * 256 + kl * 2)) ^ (((u32)(r & 7)) << 4);
                *(u16*)(lA + off) = f2bf(f);
            }
        }
        asm volatile("s_waitcnt vmcnt(0)" ::: "memory");
        __syncthreads();

        #pragma unroll
        for (int ks = 0; ks < 4; ++ks) {
            const int kk2 = (ks * 32 + kb) * 2;
            short8v a[5], b[2];
            #pragma unroll
            for (int n = 0; n < 2; ++n) {
                u32 off = ((u32)(colv[n] * 256 + kk2)) ^ xsw;
                b[n] = *(const short8v*)(lB + off);
            }
            #pragma unroll
            for (int m = 0; m < 5; ++m) {
                u32 off = ((u32)((wr * 80 + m * 16 + rA) * 256 + kk2)) ^ xsw;
                a[m] = *(const short8v*)(lA + off);
            }
            #pragma unroll
            for (int m = 0; m < 5; ++m)
                #pragma unroll
                for (int n = 0; n < 2; ++n)
                    acc[m][n] = MFMA(a[m], b[n], acc[m][n]);
        }
        __syncthreads();   // Als/Bls reads done before restage / epilogue
    }

    // epilogue: tile-col-major h2t (u16 idx = T*2048 + col*16 + row), coalesced
    const int Tb = Tbase + wr * 5;
    float csum[2] = {0.f,0.f}, csq[2] = {0.f,0.f};
    #pragma unroll
    for (int m = 0; m < 5; ++m) {
        int T = Tb + m;
        #pragma unroll
        for (int n = 0; n < 2; ++n) {
            f32x4 d = acc[m][n];
            float v0 = d[0] + bcol[n], v1 = d[1] + bcol[n];
            float v2 = d[2] + bcol[n], v3 = d[3] + bcol[n];
            csum[n] += v0 + v1 + v2 + v3;
            csq[n]  += v0*v0 + v1*v1 + v2*v2 + v3*v3;
            uint2 p; p.x = pack2(v0, v1); p.y = pack2(v2, v3);
            *(uint2*)(h2t + (size_t)T * 2048 + colv[n] * 16 + q * 4) = p;
        }
    }
    #pragma unroll
    for (int n = 0; n < 2; ++n) {
        csum[n] += __shfl_xor(csum[n], 16); csum[n] += __shfl_xor(csum[n], 32);
        csq[n]  += __shfl_xor(csq[n], 16);  csq[n]  += __shfl_xor(csq[n], 32);
    }
    if (lane < 16) {
        #pragma unroll
        for (int n = 0; n < 2; ++n) {
            atomicAdd(&slds[colv[n]], csum[n]);
            atomicAdd(&slds[128 + colv[n]], csq[n]);
        }
    }
    __syncthreads();
    if (tid < 256) atomicAdd(&gstats2[tid], slds[tid]);
}

// ---------------- out = relu(bn2(h2t)) : tiled bf16 in -> row-major f32 out ----------
__global__ __launch_bounds__(256) void k_bn2(const uint4* __restrict__ h2t4,
                                             float* __restrict__ out,
                                             const float* __restrict__ gstats2,
                                             const float* __restrict__ g2,
                                             const float* __restrict__ beta2) {
    __shared__ float fl[32 * 128];     // 16 KB: [32 rows][128 cols] f32
    __shared__ float a2s[128], b2s[128];
    const int tid = threadIdx.x;
    if (tid < 128) {
        float s = gstats2[tid], sq = gstats2[128 + tid];
        float mu = s * (1.0f / N_NODES);
        float var = sq * (1.0f / N_NODES) - mu * mu;
        float inv = rsqrtf(var + BN_EPS);
        float a = g2[tid] * inv;
        a2s[tid] = a;
        b2s[tid] = beta2[tid] - mu * a;
    }
    __syncthreads();
    const int Tbase = blockIdx.x * 2;     // 2 tiles = 32 rows per block, 3125 blocks
    // 2 tiles x 128 cols x 2 halves = 512 uint4 reads -> 2 iterations of 256 threads
    #pragma unroll
    for (int i = 0; i < 2; ++i) {
        int id = i * 256 + tid;            // 0..511
        int kl = id & 127;
        int h16 = (id >> 7) & 1;
        int Tl = id >> 8;                  // 0..1
        uint4 v = h2t4[(size_t)(Tbase + Tl) * 256 + kl * 2 + h16];
        float a = a2s[kl], b = b2s[kl];
        int r0 = Tl * 16 + h16 * 8;
        u16 hv[8] = {(u16)v.x, (u16)(v.x >> 16), (u16)v.y, (u16)(v.y >> 16),
                     (u16)v.z, (u16)(v.z >> 16), (u16)v.w, (u16)(v.w >> 16)};
        #pragma unroll
        for (int rr = 0; rr < 8; ++rr)
            fl[(r0 + rr) * 128 + kl] = fmaxf(bf2f(hv[rr]) * a + b, 0.f);
    }
    __syncthreads();
    #pragma unroll
    for (int i = 0; i < 4; ++i) {
        int id = i * 256 + tid;            // 0..1023
        int row = id >> 5;                 // 0..31
        int ch = id & 31;                  // float4 within row
        float4 vv = *(const float4*)&fl[row * 128 + ch * 4];
        ((float4*)out)[(size_t)(blockIdx.x * 32 + row) * 32 + ch] = vv;
    }
}

extern "C" void kernel_launch(void* const* d_in, const int* in_sizes, int n_in,
                              void* d_out, int out_size, void* d_ws, size_t ws_size,
                              hipStream_t stream) {
    const float* x     = (const float*)d_in[0];
    const int*   ei    = (const int*)d_in[1];
    const float* epsp  = (const float*)d_in[2];
    const float* W1    = (const float*)d_in[3];
    const float* b1    = (const float*)d_in[4];
    const float* g1    = (const float*)d_in[5];
    const float* beta1 = (const float*)d_in[6];
    const float* W2    = (const float*)d_in[7];
    const float* b2    = (const float*)d_in[8];
    const float* g2    = (const float*)d_in[9];
    const float* beta2 = (const float*)d_in[10];

    char* ws = (char*)d_ws;
    char*  aggrb   = ws;                            // [0, 25.6M) bf16 [N][128] pre-swizzled
    u16*   h2t     = (u16*)ws;                      // reuses aggrb region (gemm2 output, tiled)
    u16*   h1t     = (u16*)(ws + 25600000);         // [25.6M, 76.8M) bf16 tiled [6250][256][16]
    // nxt/head2/xb live INSIDE the h1t region (dead before gemm1 writes it):
    int2*  nxt     = (int2*)(ws + 25600000);        // 12.8 MB (next, src) per edge
    int*   head2   = (int*)(ws + 38400000);         // 800 KB (two parity chains/node)
    uint2* xb      = (uint2*)(ws + 39200000);       // 25.6 MB bf16 [N][128]
    float* gstats  = (float*)(ws + 76800000);       // 512 f32
    float* gstats2 = gstats + 512;                  // 256 f32
    char*  w1t     = ws + 76804096;                 // 64 KB bf16 W1^T swizzled
    char*  w2t     = ws + 76869632;                 // 64 KB bf16 W2^T swizzled
    float* out = (float*)d_out;

    hipMemsetAsync(head2, 0xFF, 800000, stream);    // head = -1

    k_prep<<<12500, 256, 0, stream>>>(x, ei, W1, W2, xb, head2, nxt, w1t, w2t, gstats);
    k_aggregate<<<N_NODES / 8, 256, 0, stream>>>((const uint4*)xb, nxt, head2, epsp, aggrb);
    k_gemm1<<<625, 512, 0, stream>>>(aggrb, w1t, b1, h1t, gstats);
    k_gemm2<<<625, 512, 0, stream>>>((const uint4*)h1t, w2t, b2, g1, beta1, gstats, h2t, gstats2);
    k_bn2<<<3125, 256, 0, stream>>>((const uint4*)h2t, out, gstats2, g2, beta2);
}

// Round 16
// 250.840 us; speedup vs baseline: 1.4061x; 1.4006x over previous
//
#include <hip/hip_runtime.h>
#include <hip/hip_bf16.h>

#define N_NODES 100000
#define N_EDGES 1600000
#define IN_DIM  128
#define HID     256
#define OUT_DIM 128
#define BN_EPS  1e-5f

typedef unsigned int u32;
typedef unsigned short u16;
typedef __attribute__((ext_vector_type(8))) short short8v;
typedef __attribute__((ext_vector_type(4))) float f32x4;

__device__ __forceinline__ float bf2f(u16 h) {
    return __uint_as_float(((u32)h) << 16);
}
__device__ __forceinline__ u16 f2bf(float f) {
    u32 u = __float_as_uint(f);
    u32 r = (u + 0x7fffu + ((u >> 16) & 1u)) >> 16;   // round-to-nearest-even
    return (u16)r;
}
__device__ __forceinline__ u32 pack2(float a, float b) {
    return (u32)f2bf(a) | ((u32)f2bf(b) << 16);
}
__device__ __forceinline__ void gload16(const void* g, void* l) {
    __builtin_amdgcn_global_load_lds((const __attribute__((address_space(1))) u32*)g,
                                     (__attribute__((address_space(3))) u32*)l, 16, 0, 0);
}
#define MFMA(a,b,c) __builtin_amdgcn_mfma_f32_16x16x32_bf16(a, b, c, 0, 0, 0)

// ---------------- fused prep: x->bf16, linked-list build, W transpose, stats zero ----
__global__ __launch_bounds__(256) void k_prep(const float* __restrict__ x,
                                              const int* __restrict__ ei,
                                              const float* __restrict__ W1,
                                              const float* __restrict__ W2,
                                              uint2* __restrict__ xb,
                                              int* __restrict__ head2,
                                              int2* __restrict__ nxt,
                                              char* __restrict__ w1t,
                                              char* __restrict__ w2t,
                                              float* __restrict__ gstats) {
    int t = blockIdx.x * 256 + threadIdx.x;     // grid = 12500*256 = 3.2M exact
    {   // x -> bf16 packed (t = float4 index, 3.2M total)
        float4 v = ((const float4*)x)[t];
        uint2 p;
        p.x = pack2(v.x, v.y);
        p.y = pack2(v.z, v.w);
        xb[t] = p;
    }
    if (t < N_EDGES) {   // linked-list: two parity chains per node
        int dst = ei[N_EDGES + t];
        int src = ei[t];
        int old = atomicExch(&head2[dst * 2 + (t & 1)], t);
        nxt[t] = make_int2(old, src);
    }
    if (t < 768) gstats[t] = 0.f;               // gstats(512) + gstats2(256)
    if (t < 8192) {      // W1->W1T, W2->W2T (bf16, transposed, pre-swizzled for LDS)
        u16 tmp[8];
        if (t < 4096) {
            int j = t >> 4, kc = t & 15;          // W1T: [256 j][128 k]
            #pragma unroll
            for (int i = 0; i < 8; ++i) tmp[i] = f2bf(W1[(kc * 8 + i) * HID + j]);
            u32 off = ((u32)(j * 256 + kc * 16)) ^ (((u32)(j & 7)) << 4);
            uint4 q;
            q.x = (u32)tmp[0] | ((u32)tmp[1] << 16);
            q.y = (u32)tmp[2] | ((u32)tmp[3] << 16);
            q.z = (u32)tmp[4] | ((u32)tmp[5] << 16);
            q.w = (u32)tmp[6] | ((u32)tmp[7] << 16);
            *(uint4*)(w1t + off) = q;
        } else {
            int t2 = t - 4096;
            int j = t2 >> 5, kc = t2 & 31;        // W2T: [128 j][256 k]
            #pragma unroll
            for (int i = 0; i < 8; ++i) tmp[i] = f2bf(W2[(kc * 8 + i) * OUT_DIM + j]);
            u32 off = ((u32)(j * 512 + kc * 16)) ^ (((u32)(j & 7)) << 4);
            uint4 q;
            q.x = (u32)tmp[0] | ((u32)tmp[1] << 16);
            q.y = (u32)tmp[2] | ((u32)tmp[3] << 16);
            q.z = (u32)tmp[4] | ((u32)tmp[5] << 16);
            q.w = (u32)tmp[6] | ((u32)tmp[7] << 16);
            *(uint4*)(w2t + off) = q;
        }
    }
}

// ---------------- gather-aggregate: quarter-wave per (node,parity) chain (R8 form) ----
__global__ __launch_bounds__(256) void k_aggregate(const uint4* __restrict__ xb4,
                                                   const int2* __restrict__ nxt,
                                                   const int* __restrict__ head2,
                                                   const float* __restrict__ epsp,
                                                   char* __restrict__ aggrb) {
    const int lane = threadIdx.x & 63;
    const int w = threadIdx.x >> 6;
    const int q = lane >> 4, l = lane & 15;     // quarter, lane-in-quarter
    const int nq = q >> 1, p = q & 1;           // node-in-wave, parity chain
    const int node = blockIdx.x * 8 + w * 2 + nq;

    float a[8];
    #pragma unroll
    for (int i = 0; i < 8; ++i) a[i] = 0.f;

    if (p == 0) {   // self term (1+eps)*x
        float sc = 1.0f + epsp[0];
        uint4 v = xb4[node * 16 + l];
        a[0] = bf2f((u16)v.x) * sc;  a[1] = bf2f((u16)(v.x >> 16)) * sc;
        a[2] = bf2f((u16)v.y) * sc;  a[3] = bf2f((u16)(v.y >> 16)) * sc;
        a[4] = bf2f((u16)v.z) * sc;  a[5] = bf2f((u16)(v.z >> 16)) * sc;
        a[6] = bf2f((u16)v.w) * sc;  a[7] = bf2f((u16)(v.w >> 16)) * sc;
    }
    int e = head2[node * 2 + p];
    while (e >= 0) {
        int2 nv = nxt[e];           // quarter-uniform -> broadcast
        e = nv.x;
        uint4 v = xb4[nv.y * 16 + l];
        a[0] += bf2f((u16)v.x);  a[1] += bf2f((u16)(v.x >> 16));
        a[2] += bf2f((u16)v.y);  a[3] += bf2f((u16)(v.y >> 16));
        a[4] += bf2f((u16)v.z);  a[5] += bf2f((u16)(v.z >> 16));
        a[6] += bf2f((u16)v.w);  a[7] += bf2f((u16)(v.w >> 16));
    }
    #pragma unroll
    for (int i = 0; i < 8; ++i) a[i] += __shfl_xor(a[i], 16);   // merge parities
    if (p == 0) {
        uint4 o;
        o.x = pack2(a[0], a[1]);
        o.y = pack2(a[2], a[3]);
        o.z = pack2(a[4], a[5]);
        o.w = pack2(a[6], a[7]);
        u32 b = ((u32)node * 256 + (u32)l * 16) ^ (((u32)(node & 7)) << 4);  // pre-swizzle
        *(uint4*)(aggrb + b) = o;
    }
}

// ---------------- MFMA gemm1: h1t = aggr @ W1 + b1 (bf16, tile-col-major), stats ----
// R10 form: A full-K (gload_lds), B half-K staged; LDS 74 KB; NO launch_bounds min-wave
__global__ __launch_bounds__(512) void k_gemm1(const char* __restrict__ aggrb,
                                               const char* __restrict__ w1t,
                                               const float* __restrict__ b1,
                                               u16* __restrict__ h1t,
                                               float* __restrict__ gstats) {
    __shared__ u16 Als[160 * 128];    // 40 KB swizzled, full K
    __shared__ u16 Bls[256 * 64];     // 32 KB swizzled, half K
    __shared__ float slds[512];

    const int tid = threadIdx.x, lane = tid & 63, w = tid >> 6;
    const int wr = w >> 2, wc = w & 3;
    const int base = blockIdx.x * 160;

    slds[tid] = 0.f;

    char* lA = (char*)Als;
    char* lB = (char*)Bls;
    const char* ga = aggrb + (size_t)base * 256;
    #pragma unroll
    for (int i = 0; i < 5; ++i)
        gload16(ga + i * 8192 + w * 1024 + (lane << 4), lA + i * 8192 + w * 1024);

    const int rA = lane & 15;
    const int q = lane >> 4;
    const int kb = q << 3;
    const u32 xsw = ((u32)(rA & 7)) << 4;
    int colv[4]; float bcol[4];
    #pragma unroll
    for (int n = 0; n < 4; ++n) { colv[n] = wc * 64 + n * 16 + rA; bcol[n] = b1[colv[n]]; }

    f32x4 acc[5][4];
    #pragma unroll
    for (int m = 0; m < 5; ++m)
        #pragma unroll
        for (int n = 0; n < 4; ++n) acc[m][n] = (f32x4){0.f, 0.f, 0.f, 0.f};

    for (int kh = 0; kh < 2; ++kh) {
        if (kh) __syncthreads();     // prev half's Bls reads done
        // stage B half-K: direct byte copy of physical (swizzled) half-row slices
        #pragma unroll
        for (int i = 0; i < 4; ++i) {
            int idx = i * 512 + tid;
            int j = idx >> 3, kc8 = idx & 7;
            gload16(w1t + (u32)j * 256 + (u32)kh * 128 + (u32)kc8 * 16, lB + idx * 16);
        }
        asm volatile("s_waitcnt vmcnt(0)" ::: "memory");
        __syncthreads();

        #pragma unroll
        for (int ksl = 0; ksl < 2; ++ksl) {
            const int kk2A = (kh * 64 + ksl * 32 + kb) * 2;
            const int kk2B = (ksl * 32 + kb) * 2;
            short8v a[5], b[4];
            #pragma unroll
            for (int m = 0; m < 5; ++m) {
                u32 off = ((u32)((wr * 80 + m * 16 + rA) * 256 + kk2A)) ^ xsw;
                a[m] = *(const short8v*)(lA + off);
            }
            #pragma unroll
            for (int n = 0; n < 4; ++n) {
                u32 off = ((u32)(colv[n] * 128 + kk2B)) ^ xsw;
                b[n] = *(const short8v*)(lB + off);
            }
            #pragma unroll
            for (int m = 0; m < 5; ++m)
                #pragma unroll
                for (int n = 0; n < 4; ++n)
                    acc[m][n] = MFMA(a[m], b[n], acc[m][n]);
        }
    }

    // epilogue: tile-col-major coalesced stores (wave writes dense 512B per (m,n))
    const int Tb = blockIdx.x * 10 + wr * 5;
    float csum[4] = {0.f,0.f,0.f,0.f}, csq[4] = {0.f,0.f,0.f,0.f};
    #pragma unroll
    for (int m = 0; m < 5; ++m) {
        int T = Tb + m;
        #pragma unroll
        for (int n = 0; n < 4; ++n) {
            f32x4 d = acc[m][n];
            float v0 = d[0] + bcol[n], v1 = d[1] + bcol[n];
            float v2 = d[2] + bcol[n], v3 = d[3] + bcol[n];
            csum[n] += v0 + v1 + v2 + v3;
            csq[n]  += v0*v0 + v1*v1 + v2*v2 + v3*v3;
            uint2 p; p.x = pack2(v0, v1); p.y = pack2(v2, v3);
            *(uint2*)(h1t + (size_t)T * 4096 + colv[n] * 16 + q * 4) = p;
        }
    }
    #pragma unroll
    for (int n = 0; n < 4; ++n) {
        csum[n] += __shfl_xor(csum[n], 16); csum[n] += __shfl_xor(csum[n], 32);
        csq[n]  += __shfl_xor(csq[n], 16);  csq[n]  += __shfl_xor(csq[n], 32);
    }
    if (lane < 16) {
        #pragma unroll
        for (int n = 0; n < 4; ++n) {
            atomicAdd(&slds[colv[n]], csum[n]);
            atomicAdd(&slds[256 + colv[n]], csq[n]);
        }
    }
    __syncthreads();
    atomicAdd(&gstats[tid], slds[tid]);
}

// ---------------- MFMA gemm2: h2t = relu(bn1(h1t)) @ W2 + b2 (bf16 tiled), stats2 ----
// R10 form + B gloads issued BEFORE the A restage (latency hides under VALU work)
__global__ __launch_bounds__(512) void k_gemm2(const uint4* __restrict__ h1t4,
                                               const char* __restrict__ w2t,
                                               const float* __restrict__ b2,
                                               const float* __restrict__ g1,
                                               const float* __restrict__ beta1,
                                               const float* __restrict__ gstats,
                                               u16* __restrict__ h2t,
                                               float* __restrict__ gstats2) {
    __shared__ u16 Als[160 * 128];    // 40 KB (K half), swizzled [row][k] u16
    __shared__ u16 Bls[128 * 128];    // 32 KB (K half), swizzled
    __shared__ float a1s[256], b1s[256];
    __shared__ float slds[256];

    const int tid = threadIdx.x, lane = tid & 63, w = tid >> 6;
    const int wr = w >> 2, wc = w & 3;
    const int Tbase = blockIdx.x * 10;

    if (tid < 256) {
        float s = gstats[tid], sq = gstats[256 + tid];
        float mu = s * (1.0f / N_NODES);
        float var = sq * (1.0f / N_NODES) - mu * mu;
        float inv = rsqrtf(var + BN_EPS);
        float a = g1[tid] * inv;
        a1s[tid] = a;
        b1s[tid] = beta1[tid] - mu * a;
        slds[tid] = 0.f;
    }

    char* lA = (char*)Als;
    char* lB = (char*)Bls;

    const int rA = lane & 15;
    const int q = lane >> 4;
    const int kb = q << 3;
    const u32 xsw = ((u32)(rA & 7)) << 4;
    int colv[2]; float bcol[2];
    #pragma unroll
    for (int n = 0; n < 2; ++n) { colv[n] = wc * 32 + n * 16 + rA; bcol[n] = b2[colv[n]]; }

    __syncthreads();   // a1s/b1s ready

    f32x4 acc[5][2];
    #pragma unroll
    for (int m = 0; m < 5; ++m)
        #pragma unroll
        for (int n = 0; n < 2; ++n) acc[m][n] = (f32x4){0.f, 0.f, 0.f, 0.f};

    for (int kh = 0; kh < 2; ++kh) {
        // issue B half-K gloads FIRST (latency hides under the A restage below)
        #pragma unroll
        for (int i = 0; i < 4; ++i) {
            int idx = i * 512 + tid;
            int j = idx >> 4, kc16 = idx & 15;
            u32 src = (u32)j * 512 + (u32)kh * 256 + (u32)kc16 * 16;   // swizzle preserved
            gload16(w2t + src, lB + idx * 16);
        }
        // stage A half-tile with BN1+ReLU from tile-col-major h1t (tile = 512 uint4)
        #pragma unroll
        for (int i = 0; i < 5; ++i) {
            int id = i * 512 + tid;        // 0..2559
            int kl = id & 127;
            int h16 = (id >> 7) & 1;
            int Tl = id >> 8;              // 0..9
            int kg = kh * 128 + kl;
            uint4 v = h1t4[(size_t)(Tbase + Tl) * 512 + kg * 2 + h16];
            float a = a1s[kg], b = b1s[kg];
            int r0 = Tl * 16 + h16 * 8;
            u16 hv[8] = {(u16)v.x, (u16)(v.x >> 16), (u16)v.y, (u16)(v.y >> 16),
                         (u16)v.z, (u16)(v.z >> 16), (u16)v.w, (u16)(v.w >> 16)};
            #pragma unroll
            for (int rr = 0; rr < 8; ++rr) {
                float f = fmaxf(bf2f(hv[rr]) * a + b, 0.f);
                int r = r0 + rr;
                u32 off = ((u32)(r * 256 + kl * 2)) ^ (((u32)(r & 7)) << 4);
                *(u16*)(lA + off) = f2bf(f);
            }
        }
        asm volatile("s_waitcnt vmcnt(0)" ::: "memory");
        __syncthreads();

        #pragma unroll
        for (int ks = 0; ks < 4; ++ks) {
            const int kk2 = (ks * 32 + kb) * 2;
            short8v a[5], b[2];
            #pragma unroll
            for (int n = 0; n < 2; ++n) {
                u32 off = ((u32)(colv[n] * 256 + kk2)) ^ xsw;
                b[n] = *(const short8v*)(lB + off);
            }
            #pragma unroll
            for (int m = 0; m < 5; ++m) {
                u32 off = ((u32)((wr * 80 + m * 16 + rA) * 256 + kk2)) ^ xsw;
                a[m] = *(const short8v*)(lA + off);
            }
            #pragma unroll
            for (int m = 0; m < 5; ++m)
                #pragma unroll
                for (int n = 0; n < 2; ++n)
                    acc[m][n] = MFMA(a[m], b[n], acc[m][n]);
        }
        __syncthreads();   // Als/Bls reads done before restage / epilogue
    }

    // epilogue: tile-col-major h2t (u16 idx = T*2048 + col*16 + row), coalesced
    const int Tb = Tbase + wr * 5;
    float csum[2] = {0.f,0.f}, csq[2] = {0.f,0.f};
    #pragma unroll
    for (int m = 0; m < 5; ++m) {
        int T = Tb + m;
        #pragma unroll
        for (int n = 0; n < 2; ++n) {
            f32x4 d = acc[m][n];
            float v0 = d[0] + bcol[n], v1 = d[1] + bcol[n];
            float v2 = d[2] + bcol[n], v3 = d[3] + bcol[n];
            csum[n] += v0 + v1 + v2 + v3;
            csq[n]  += v0*v0 + v1*v1 + v2*v2 + v3*v3;
            uint2 p; p.x = pack2(v0, v1); p.y = pack2(v2, v3);
            *(uint2*)(h2t + (size_t)T * 2048 + colv[n] * 16 + q * 4) = p;
        }
    }
    #pragma unroll
    for (int n = 0; n < 2; ++n) {
        csum[n] += __shfl_xor(csum[n], 16); csum[n] += __shfl_xor(csum[n], 32);
        csq[n]  += __shfl_xor(csq[n], 16);  csq[n]  += __shfl_xor(csq[n], 32);
    }
    if (lane < 16) {
        #pragma unroll
        for (int n = 0; n < 2; ++n) {
            atomicAdd(&slds[colv[n]], csum[n]);
            atomicAdd(&slds[128 + colv[n]], csq[n]);
        }
    }
    __syncthreads();
    if (tid < 256) atomicAdd(&gstats2[tid], slds[tid]);
}

// ---------------- out = relu(bn2(h2t)) : tiled bf16 in -> row-major f32 out ----------
__global__ __launch_bounds__(256) void k_bn2(const uint4* __restrict__ h2t4,
                                             float* __restrict__ out,
                                             const float* __restrict__ gstats2,
                                             const float* __restrict__ g2,
                                             const float* __restrict__ beta2) {
    __shared__ float fl[32 * 128];     // 16 KB: [32 rows][128 cols] f32
    __shared__ float a2s[128], b2s[128];
    const int tid = threadIdx.x;
    if (tid < 128) {
        float s = gstats2[tid], sq = gstats2[128 + tid];
        float mu = s * (1.0f / N_NODES);
        float var = sq * (1.0f / N_NODES) - mu * mu;
        float inv = rsqrtf(var + BN_EPS);
        float a = g2[tid] * inv;
        a2s[tid] = a;
        b2s[tid] = beta2[tid] - mu * a;
    }
    __syncthreads();
    const int Tbase = blockIdx.x * 2;     // 2 tiles = 32 rows per block, 3125 blocks
    // 2 tiles x 128 cols x 2 halves = 512 uint4 reads -> 2 iterations of 256 threads
    #pragma unroll
    for (int i = 0; i < 2; ++i) {
        int id = i * 256 + tid;            // 0..511
        int kl = id & 127;
        int h16 = (id >> 7) & 1;
        int Tl = id >> 8;                  // 0..1
        uint4 v = h2t4[(size_t)(Tbase + Tl) * 256 + kl * 2 + h16];
        float a = a2s[kl], b = b2s[kl];
        int r0 = Tl * 16 + h16 * 8;
        u16 hv[8] = {(u16)v.x, (u16)(v.x >> 16), (u16)v.y, (u16)(v.y >> 16),
                     (u16)v.z, (u16)(v.z >> 16), (u16)v.w, (u16)(v.w >> 16)};
        #pragma unroll
        for (int rr = 0; rr < 8; ++rr)
            fl[(r0 + rr) * 128 + kl] = fmaxf(bf2f(hv[rr]) * a + b, 0.f);
    }
    __syncthreads();
    #pragma unroll
    for (int i = 0; i < 4; ++i) {
        int id = i * 256 + tid;            // 0..1023
        int row = id >> 5;                 // 0..31
        int ch = id & 31;                  // float4 within row
        float4 vv = *(const float4*)&fl[row * 128 + ch * 4];
        ((float4*)out)[(size_t)(blockIdx.x * 32 + row) * 32 + ch] = vv;
    }
}

extern "C" void kernel_launch(void* const* d_in, const int* in_sizes, int n_in,
                              void* d_out, int out_size, void* d_ws, size_t ws_size,
                              hipStream_t stream) {
    const float* x     = (const float*)d_in[0];
    const int*   ei    = (const int*)d_in[1];
    const float* epsp  = (const float*)d_in[2];
    const float* W1    = (const float*)d_in[3];
    const float* b1    = (const float*)d_in[4];
    const float* g1    = (const float*)d_in[5];
    const float* beta1 = (const float*)d_in[6];
    const float* W2    = (const float*)d_in[7];
    const float* b2    = (const float*)d_in[8];
    const float* g2    = (const float*)d_in[9];
    const float* beta2 = (const float*)d_in[10];

    char* ws = (char*)d_ws;
    char*  aggrb   = ws;                            // [0, 25.6M) bf16 [N][128] pre-swizzled
    u16*   h2t     = (u16*)ws;                      // reuses aggrb region (gemm2 output, tiled)
    u16*   h1t     = (u16*)(ws + 25600000);         // [25.6M, 76.8M) bf16 tiled [6250][256][16]
    // nxt/head2/xb live INSIDE the h1t region (dead before gemm1 writes it):
    int2*  nxt     = (int2*)(ws + 25600000);        // 12.8 MB (next, src) per edge
    int*   head2   = (int*)(ws + 38400000);         // 800 KB (two parity chains/node)
    uint2* xb      = (uint2*)(ws + 39200000);       // 25.6 MB bf16 [N][128]
    float* gstats  = (float*)(ws + 76800000);       // 512 f32
    float* gstats2 = gstats + 512;                  // 256 f32
    char*  w1t     = ws + 76804096;                 // 64 KB bf16 W1^T swizzled
    char*  w2t     = ws + 76869632;                 // 64 KB bf16 W2^T swizzled
    float* out = (float*)d_out;

    hipMemsetAsync(head2, 0xFF, 800000, stream);    // head = -1

    k_prep<<<12500, 256, 0, stream>>>(x, ei, W1, W2, xb, head2, nxt, w1t, w2t, gstats);
    k_aggregate<<<N_NODES / 8, 256, 0, stream>>>((const uint4*)xb, nxt, head2, epsp, aggrb);
    k_gemm1<<<625, 512, 0, stream>>>(aggrb, w1t, b1, h1t, gstats);
    k_gemm2<<<625, 512, 0, stream>>>((const uint4*)h1t, w2t, b2, g1, beta1, gstats, h2t, gstats2);
    k_bn2<<<3125, 256, 0, stream>>>((const uint4*)h2t, out, gstats2, g2, beta2);
}